// Round 1
// baseline (2940.910 us; speedup 1.0000x reference)
//
#include <hip/hip_runtime.h>
#include <hip/hip_bf16.h>

#define LYR 6
#define H 768
#define NH 12
#define HD 64
#define FF 3072
#define T 512
#define BB 4
#define M_TOK 2048
#define SCALE 0.125f

typedef __hip_bfloat16 bf16;
typedef __attribute__((ext_vector_type(8))) short short8;
typedef __attribute__((ext_vector_type(4))) float f32x4;

// ---------------- block reduction helpers (256 threads) ----------------
__device__ __forceinline__ float block_sum256(float v) {
    __shared__ float sm[4];
    #pragma unroll
    for (int o = 32; o > 0; o >>= 1) v += __shfl_down(v, o);
    if ((threadIdx.x & 63) == 0) sm[threadIdx.x >> 6] = v;
    __syncthreads();
    float r = sm[0] + sm[1] + sm[2] + sm[3];
    __syncthreads();
    return r;
}

__device__ __forceinline__ float block_max256(float v) {
    __shared__ float sm[4];
    #pragma unroll
    for (int o = 32; o > 0; o >>= 1) v = fmaxf(v, __shfl_down(v, o));
    if ((threadIdx.x & 63) == 0) sm[threadIdx.x >> 6] = v;
    __syncthreads();
    float r = fmaxf(fmaxf(sm[0], sm[1]), fmaxf(sm[2], sm[3]));
    __syncthreads();
    return r;
}

// ---------------- GEMM core: C[128 x NT*32] = A(128,K) * Bt(NT*32,K)^T ----
// A row-major (lda), Bt row-major (ldb) i.e. B transposed. 256 threads.
// Wave grid 2x2; each wave computes 64 x (NT*16) via 4 x NT mfma 16x16x32.
template<int NT>
__device__ __forceinline__ void gemm_core(
    const bf16* __restrict__ A, int lda,
    const bf16* __restrict__ Bt, int ldb,
    int K, f32x4 acc[4][NT])
{
    constexpr int BN = NT * 32;
    __shared__ bf16 sA[128 * 32];
    __shared__ bf16 sB[BN * 32];
    const int tid = threadIdx.x;
    const int wave = tid >> 6, lane = tid & 63;
    const int wr = wave >> 1, wc = wave & 1;
    const int quad = lane >> 4, m16 = lane & 15;

    for (int k0 = 0; k0 < K; k0 += 32) {
        uint4 aR[2];
        uint4 bR[BN / 64];
        #pragma unroll
        for (int i = 0; i < 2; i++) {
            int c = tid + i * 256; int r = c >> 2, k8 = c & 3;
            aR[i] = *(const uint4*)(A + (size_t)r * lda + k0 + k8 * 8);
        }
        #pragma unroll
        for (int i = 0; i < BN / 64; i++) {
            int c = tid + i * 256; int r = c >> 2, k8 = c & 3;
            bR[i] = *(const uint4*)(Bt + (size_t)r * ldb + k0 + k8 * 8);
        }
        __syncthreads();
        #pragma unroll
        for (int i = 0; i < 2; i++) {
            int c = tid + i * 256;
            *(uint4*)(sA + c * 8) = aR[i];
        }
        #pragma unroll
        for (int i = 0; i < BN / 64; i++) {
            int c = tid + i * 256;
            *(uint4*)(sB + c * 8) = bR[i];
        }
        __syncthreads();
        short8 af[4], bfr[NT];
        #pragma unroll
        for (int mt = 0; mt < 4; mt++) {
            int row = wr * 64 + mt * 16 + m16;
            af[mt] = *(const short8*)(sA + row * 32 + quad * 8);
        }
        #pragma unroll
        for (int nt = 0; nt < NT; nt++) {
            int row = wc * NT * 16 + nt * 16 + m16;
            bfr[nt] = *(const short8*)(sB + row * 32 + quad * 8);
        }
        #pragma unroll
        for (int mt = 0; mt < 4; mt++)
            #pragma unroll
            for (int nt = 0; nt < NT; nt++)
                acc[mt][nt] = __builtin_amdgcn_mfma_f32_16x16x32_bf16(
                    af[mt], bfr[nt], acc[mt][nt], 0, 0, 0);
    }
}

#define EPI_IDX() \
    const int tid = threadIdx.x; \
    const int wave = tid >> 6, lane = tid & 63; \
    const int wr = wave >> 1, wc = wave & 1; \
    const int quad = lane >> 4, m16 = lane & 15;

// ---------------- weight transpose + convert: src (R,C) f32 -> dst (C,R) bf16
__global__ __launch_bounds__(256) void k_transpose(
    const float* __restrict__ src, bf16* __restrict__ dst, int R, int C)
{
    __shared__ float tile[32][33];
    const int l = blockIdx.z;
    src += (size_t)l * R * C;
    dst += (size_t)l * R * C;
    int c0 = blockIdx.x * 32, r0 = blockIdx.y * 32;
    int tx = threadIdx.x & 31, ty = threadIdx.x >> 5; // 32 x 8
    #pragma unroll
    for (int i = 0; i < 32; i += 8)
        tile[ty + i][tx] = src[(size_t)(r0 + ty + i) * C + c0 + tx];
    __syncthreads();
    #pragma unroll
    for (int i = 0; i < 32; i += 8)
        dst[(size_t)(c0 + ty + i) * R + r0 + tx] = __float2bfloat16(tile[tx][ty + i]);
}

// ---------------- layernorm: x (2048,768) f32 -> out bf16 --------------
__global__ __launch_bounds__(256) void k_ln(
    const float* __restrict__ x, const float* __restrict__ g,
    const float* __restrict__ b, bf16* __restrict__ out)
{
    const int row = blockIdx.x;
    const float* xr = x + (size_t)row * H;
    const int tid = threadIdx.x;
    float v0 = xr[tid], v1 = xr[tid + 256], v2 = xr[tid + 512];
    float mean = block_sum256(v0 + v1 + v2) * (1.0f / H);
    float d0 = v0 - mean, d1 = v1 - mean, d2 = v2 - mean;
    float var = block_sum256(d0 * d0 + d1 * d1 + d2 * d2) * (1.0f / H);
    float rs = rsqrtf(var + 1e-5f);
    bf16* orow = out + (size_t)row * H;
    orow[tid]       = __float2bfloat16(d0 * rs * g[tid]       + b[tid]);
    orow[tid + 256] = __float2bfloat16(d1 * rs * g[tid + 256] + b[tid + 256]);
    orow[tid + 512] = __float2bfloat16(d2 * rs * g[tid + 512] + b[tid + 512]);
}

// ---------------- fused QKV GEMM ---------------------------------------
// grid (16, 18): y -> mat = y/6 (0=q,1=k,2=v), col block = y%6
__global__ __launch_bounds__(256, 2) void k_qkv(
    const bf16* __restrict__ h,
    const bf16* __restrict__ Wqt, const bf16* __restrict__ Wkt, const bf16* __restrict__ Wvt,
    const float* __restrict__ bq, const float* __restrict__ bk, const float* __restrict__ bv,
    bf16* __restrict__ qb, bf16* __restrict__ kb, bf16* __restrict__ vtb)
{
    const int bm = blockIdx.x, bc = blockIdx.y;
    const int mat = bc / 6, nc = (bc % 6) * 128;
    const bf16* Bt = (mat == 0 ? Wqt : (mat == 1 ? Wkt : Wvt)) + (size_t)nc * H;
    const float* bias = (mat == 0 ? bq : (mat == 1 ? bk : bv));
    f32x4 acc[4][4];
    for (int a = 0; a < 4; a++) for (int bb = 0; bb < 4; bb++)
        for (int i = 0; i < 4; i++) acc[a][bb][i] = 0.0f;
    gemm_core<4>(h + (size_t)bm * 128 * H, H, Bt, H, H, acc);
    EPI_IDX();
    #pragma unroll
    for (int mt = 0; mt < 4; mt++)
        #pragma unroll
        for (int nt = 0; nt < 4; nt++)
            #pragma unroll
            for (int i = 0; i < 4; i++) {
                int r = bm * 128 + wr * 64 + mt * 16 + quad * 4 + i;
                int c = nc + wc * 64 + nt * 16 + m16;
                float v = acc[mt][nt][i] + bias[c];
                int t = r >> 2, b = r & 3, hh = c >> 6, d = c & 63;
                int n = b * NH + hh;
                if (mat == 0)
                    qb[((size_t)(n * T + t)) * HD + d] = __float2bfloat16(v * SCALE);
                else if (mat == 1)
                    kb[((size_t)(n * T + t)) * HD + d] = __float2bfloat16(v);
                else
                    vtb[((size_t)(n * HD + d)) * T + t] = __float2bfloat16(v);
            }
}

// ---------------- scores GEMM: per head S = q k^T + bias, *decay, mask --
// grid (4, 4, 48)
__global__ __launch_bounds__(256, 2) void k_scores(
    const bf16* __restrict__ qb, const bf16* __restrict__ kb,
    const float* __restrict__ abias, const float* __restrict__ decay,
    const int* __restrict__ am, float* __restrict__ sb)
{
    const int n = blockIdx.z;
    const int b = n / NH;
    f32x4 acc[4][4];
    for (int a = 0; a < 4; a++) for (int bb = 0; bb < 4; bb++)
        for (int i = 0; i < 4; i++) acc[a][bb][i] = 0.0f;
    gemm_core<4>(qb + ((size_t)n * T + blockIdx.x * 128) * HD, HD,
                 kb + ((size_t)n * T + blockIdx.y * 128) * HD, HD, HD, acc);
    EPI_IDX();
    #pragma unroll
    for (int mt = 0; mt < 4; mt++)
        #pragma unroll
        for (int nt = 0; nt < 4; nt++)
            #pragma unroll
            for (int i = 0; i < 4; i++) {
                int t = blockIdx.x * 128 + wr * 64 + mt * 16 + quad * 4 + i;
                int s = blockIdx.y * 128 + wc * 64 + nt * 16 + m16;
                size_t idx = ((size_t)n * T + t) * T + s;
                float v = (acc[mt][nt][i] + abias[idx]) * decay[idx];
                bool dead = (!(am[b * T + t] && am[b * T + s])) || (t >= 1 && s == 0);
                sb[idx] = dead ? -__builtin_inff() : v;
            }
}

// ---------------- softmax over s: sb (48,512,512) f32 -> pb bf16 --------
__global__ __launch_bounds__(256) void k_softmax(
    const float* __restrict__ sb, bf16* __restrict__ pb)
{
    const int n = blockIdx.y, t = blockIdx.x;
    const float* row = sb + ((size_t)n * T + t) * T;
    const int tid = threadIdx.x;
    float a0 = row[tid], a1 = row[tid + 256];
    float m = block_max256(fmaxf(a0, a1));
    float e0 = expf(a0 - m), e1 = expf(a1 - m);
    float inv = 1.0f / block_sum256(e0 + e1);
    bf16* orow = pb + ((size_t)n * T + t) * T;
    orow[tid]       = __float2bfloat16(e0 * inv);
    orow[tid + 256] = __float2bfloat16(e1 * inv);
}

// ---------------- PV GEMM: attn = P @ V, write token-major bf16 ---------
// grid (4, 1, 48), tile 128x64
__global__ __launch_bounds__(256, 2) void k_pv(
    const bf16* __restrict__ pb, const bf16* __restrict__ vtb,
    bf16* __restrict__ ab)
{
    const int n = blockIdx.z;
    f32x4 acc[4][2];
    for (int a = 0; a < 4; a++) for (int bb = 0; bb < 2; bb++)
        for (int i = 0; i < 4; i++) acc[a][bb][i] = 0.0f;
    gemm_core<2>(pb + ((size_t)n * T + blockIdx.x * 128) * T, T,
                 vtb + (size_t)n * HD * T, T, T, acc);
    EPI_IDX();
    const int b = n / NH, hh = n % NH;
    #pragma unroll
    for (int mt = 0; mt < 4; mt++)
        #pragma unroll
        for (int nt = 0; nt < 2; nt++)
            #pragma unroll
            for (int i = 0; i < 4; i++) {
                int t = blockIdx.x * 128 + wr * 64 + mt * 16 + quad * 4 + i;
                int d = wc * 32 + nt * 16 + m16;
                ab[((size_t)(t * BB + b)) * H + hh * HD + d] = __float2bfloat16(acc[mt][nt][i]);
            }
}

// ---------------- attn out proj + residual ------------------------------
__global__ __launch_bounds__(256, 2) void k_out(
    const bf16* __restrict__ ab, const bf16* __restrict__ Wot,
    const float* __restrict__ bo, float* __restrict__ x)
{
    const int bm = blockIdx.x, bn = blockIdx.y;
    f32x4 acc[4][4];
    for (int a = 0; a < 4; a++) for (int bb = 0; bb < 4; bb++)
        for (int i = 0; i < 4; i++) acc[a][bb][i] = 0.0f;
    gemm_core<4>(ab + (size_t)bm * 128 * H, H, Wot + (size_t)bn * 128 * H, H, H, acc);
    EPI_IDX();
    #pragma unroll
    for (int mt = 0; mt < 4; mt++)
        #pragma unroll
        for (int nt = 0; nt < 4; nt++)
            #pragma unroll
            for (int i = 0; i < 4; i++) {
                int r = bm * 128 + wr * 64 + mt * 16 + quad * 4 + i;
                int c = bn * 128 + wc * 64 + nt * 16 + m16;
                size_t idx = (size_t)r * H + c;
                x[idx] = x[idx] + acc[mt][nt][i] + bo[c];
            }
}

// ---------------- FFN1 + gelu -------------------------------------------
__global__ __launch_bounds__(256, 2) void k_ffn1(
    const bf16* __restrict__ h, const bf16* __restrict__ W1t,
    const float* __restrict__ b1, bf16* __restrict__ gb)
{
    const int bm = blockIdx.x, bn = blockIdx.y;
    f32x4 acc[4][4];
    for (int a = 0; a < 4; a++) for (int bb = 0; bb < 4; bb++)
        for (int i = 0; i < 4; i++) acc[a][bb][i] = 0.0f;
    gemm_core<4>(h + (size_t)bm * 128 * H, H, W1t + (size_t)bn * 128 * H, H, H, acc);
    EPI_IDX();
    #pragma unroll
    for (int mt = 0; mt < 4; mt++)
        #pragma unroll
        for (int nt = 0; nt < 4; nt++)
            #pragma unroll
            for (int i = 0; i < 4; i++) {
                int r = bm * 128 + wr * 64 + mt * 16 + quad * 4 + i;
                int c = bn * 128 + wc * 64 + nt * 16 + m16;
                float u = acc[mt][nt][i] + b1[c];
                float gl = 0.5f * u * (1.0f + tanhf(0.7978845608028654f * (u + 0.044715f * u * u * u)));
                gb[(size_t)r * FF + c] = __float2bfloat16(gl);
            }
}

// ---------------- FFN2 + residual ---------------------------------------
__global__ __launch_bounds__(256, 2) void k_ffn2(
    const bf16* __restrict__ gb, const bf16* __restrict__ W2t,
    const float* __restrict__ b2, float* __restrict__ x)
{
    const int bm = blockIdx.x, bn = blockIdx.y;
    f32x4 acc[4][4];
    for (int a = 0; a < 4; a++) for (int bb = 0; bb < 4; bb++)
        for (int i = 0; i < 4; i++) acc[a][bb][i] = 0.0f;
    gemm_core<4>(gb + (size_t)bm * 128 * FF, FF, W2t + (size_t)bn * 128 * FF, FF, FF, acc);
    EPI_IDX();
    #pragma unroll
    for (int mt = 0; mt < 4; mt++)
        #pragma unroll
        for (int nt = 0; nt < 4; nt++)
            #pragma unroll
            for (int i = 0; i < 4; i++) {
                int r = bm * 128 + wr * 64 + mt * 16 + quad * 4 + i;
                int c = bn * 128 + wc * 64 + nt * 16 + m16;
                size_t idx = (size_t)r * H + c;
                x[idx] = x[idx] + acc[mt][nt][i] + b2[c];
            }
}

// ---------------- host ---------------------------------------------------
extern "C" void kernel_launch(void* const* d_in, const int* in_sizes, int n_in,
                              void* d_out, int out_size, void* d_ws, size_t ws_size,
                              hipStream_t stream) {
    const float* x_in  = (const float*)d_in[0];
    const float* abias = (const float*)d_in[1];
    const float* decay = (const float*)d_in[2];
    const int*   am    = (const int*)d_in[3];
    const float* Wq = (const float*)d_in[4];
    const float* bq = (const float*)d_in[5];
    const float* Wk = (const float*)d_in[6];
    const float* bk = (const float*)d_in[7];
    const float* Wv = (const float*)d_in[8];
    const float* bv = (const float*)d_in[9];
    const float* Wo = (const float*)d_in[10];
    const float* bo = (const float*)d_in[11];
    const float* ln1g = (const float*)d_in[12];
    const float* ln1b = (const float*)d_in[13];
    const float* ln2g = (const float*)d_in[14];
    const float* ln2b = (const float*)d_in[15];
    const float* W1 = (const float*)d_in[16];
    const float* b1 = (const float*)d_in[17];
    const float* W2 = (const float*)d_in[18];
    const float* b2 = (const float*)d_in[19];
    float* x = (float*)d_out;

    char* p = (char*)d_ws;
    auto alloc = [&](size_t bytes) {
        char* r = p;
        p += (bytes + 255) & ~(size_t)255;
        return r;
    };
    bf16* Wqt = (bf16*)alloc((size_t)LYR * H * H * 2);
    bf16* Wkt = (bf16*)alloc((size_t)LYR * H * H * 2);
    bf16* Wvt = (bf16*)alloc((size_t)LYR * H * H * 2);
    bf16* Wot = (bf16*)alloc((size_t)LYR * H * H * 2);
    bf16* W1t = (bf16*)alloc((size_t)LYR * H * FF * 2);
    bf16* W2t = (bf16*)alloc((size_t)LYR * H * FF * 2);
    bf16* hbuf = (bf16*)alloc((size_t)M_TOK * H * 2);
    bf16* qb   = (bf16*)alloc((size_t)BB * NH * T * HD * 2);   // also reused as ab
    bf16* kb   = (bf16*)alloc((size_t)BB * NH * T * HD * 2);
    bf16* vtb  = (bf16*)alloc((size_t)BB * NH * T * HD * 2);
    float* sb  = (float*)alloc((size_t)BB * NH * T * T * 4);
    bf16* pb   = (bf16*)alloc((size_t)BB * NH * T * T * 2);    // also reused as gb
    bf16* ab = qb;
    bf16* gb = pb;

    hipMemcpyAsync(x, x_in, (size_t)M_TOK * H * 4, hipMemcpyDeviceToDevice, stream);

    dim3 blk(256);
    k_transpose<<<dim3(H / 32, H / 32, LYR), blk, 0, stream>>>(Wq, Wqt, H, H);
    k_transpose<<<dim3(H / 32, H / 32, LYR), blk, 0, stream>>>(Wk, Wkt, H, H);
    k_transpose<<<dim3(H / 32, H / 32, LYR), blk, 0, stream>>>(Wv, Wvt, H, H);
    k_transpose<<<dim3(H / 32, H / 32, LYR), blk, 0, stream>>>(Wo, Wot, H, H);
    k_transpose<<<dim3(FF / 32, H / 32, LYR), blk, 0, stream>>>(W1, W1t, H, FF);
    k_transpose<<<dim3(H / 32, FF / 32, LYR), blk, 0, stream>>>(W2, W2t, FF, H);

    for (int l = 0; l < LYR; l++) {
        size_t wo = (size_t)l * H * H;
        size_t wf = (size_t)l * H * FF;
        k_ln<<<dim3(M_TOK), blk, 0, stream>>>(x, ln1g + l * H, ln1b + l * H, hbuf);
        k_qkv<<<dim3(16, 18), blk, 0, stream>>>(hbuf, Wqt + wo, Wkt + wo, Wvt + wo,
                                                bq + l * H, bk + l * H, bv + l * H,
                                                qb, kb, vtb);
        k_scores<<<dim3(4, 4, 48), blk, 0, stream>>>(qb, kb, abias, decay, am, sb);
        k_softmax<<<dim3(T, 48), blk, 0, stream>>>(sb, pb);
        k_pv<<<dim3(4, 1, 48), blk, 0, stream>>>(pb, vtb, ab);
        k_out<<<dim3(16, 6), blk, 0, stream>>>(ab, Wot + wo, bo + l * H, x);
        k_ln<<<dim3(M_TOK), blk, 0, stream>>>(x, ln2g + l * H, ln2b + l * H, hbuf);
        k_ffn1<<<dim3(16, 24), blk, 0, stream>>>(hbuf, W1t + wf, b1 + l * FF, gb);
        k_ffn2<<<dim3(16, 6), blk, 0, stream>>>(gb, W2t + wf, b2 + l * H, x);
    }
}

// Round 2
// 1579.224 us; speedup vs baseline: 1.8622x; 1.8622x over previous
//
#include <hip/hip_runtime.h>
#include <hip/hip_bf16.h>

#define LYR 6
#define H 768
#define NH 12
#define HD 64
#define FF 3072
#define T 512
#define BB 4
#define M_TOK 2048
#define SCALE 0.125f

typedef __hip_bfloat16 bf16;
typedef __attribute__((ext_vector_type(8))) short short8;
typedef __attribute__((ext_vector_type(4))) float f32x4;

// ---------------- block reduction helpers (256 threads) ----------------
__device__ __forceinline__ float block_sum256(float v) {
    __shared__ float sm[4];
    #pragma unroll
    for (int o = 32; o > 0; o >>= 1) v += __shfl_down(v, o);
    if ((threadIdx.x & 63) == 0) sm[threadIdx.x >> 6] = v;
    __syncthreads();
    float r = sm[0] + sm[1] + sm[2] + sm[3];
    __syncthreads();
    return r;
}

__device__ __forceinline__ float block_max256(float v) {
    __shared__ float sm[4];
    #pragma unroll
    for (int o = 32; o > 0; o >>= 1) v = fmaxf(v, __shfl_down(v, o));
    if ((threadIdx.x & 63) == 0) sm[threadIdx.x >> 6] = v;
    __syncthreads();
    float r = fmaxf(fmaxf(sm[0], sm[1]), fmaxf(sm[2], sm[3]));
    __syncthreads();
    return r;
}

// async global->LDS, 16 B per lane; lds base must be wave-uniform
__device__ __forceinline__ void gload_lds16(const bf16* g, bf16* l) {
    __builtin_amdgcn_global_load_lds(
        (const __attribute__((address_space(1))) void*)g,
        (__attribute__((address_space(3))) void*)l, 16, 0, 0);
}

// ---------------- GEMM core: C[128 x NT*32] = A(128,K) * Bt(NT*32,K)^T ----
// A row-major (lda), Bt row-major (ldb) i.e. B transposed. 256 threads.
// Wave grid 2x2; each wave computes 64 x (NT*16) via 4 x NT mfma 16x16x32.
// Staging via global_load_lds width=16 (m97 structure, 2 barriers/K-step).
template<int NT>
__device__ __forceinline__ void gemm_core(
    const bf16* __restrict__ A, int lda,
    const bf16* __restrict__ Bt, int ldb,
    int K, f32x4 acc[4][NT])
{
    constexpr int BN = NT * 32;
    __shared__ bf16 sA[128 * 32];
    __shared__ bf16 sB[BN * 32];
    const int tid = threadIdx.x;
    const int wave = tid >> 6, lane = tid & 63;
    const int wr = wave >> 1, wc = wave & 1;
    const int quad = lane >> 4, m16 = lane & 15;

    for (int k0 = 0; k0 < K; k0 += 32) {
        #pragma unroll
        for (int i = 0; i < 2; i++) {
            int c = tid + i * 256; int r = c >> 2, k8 = c & 3;
            gload_lds16(A + (size_t)r * lda + k0 + k8 * 8,
                        sA + (i * 256 + wave * 64) * 8);
        }
        #pragma unroll
        for (int i = 0; i < BN / 64; i++) {
            int c = tid + i * 256; int r = c >> 2, k8 = c & 3;
            gload_lds16(Bt + (size_t)r * ldb + k0 + k8 * 8,
                        sB + (i * 256 + wave * 64) * 8);
        }
        __syncthreads();
        short8 af[4], bfr[NT];
        #pragma unroll
        for (int mt = 0; mt < 4; mt++) {
            int row = wr * 64 + mt * 16 + m16;
            af[mt] = *(const short8*)(sA + row * 32 + quad * 8);
        }
        #pragma unroll
        for (int nt = 0; nt < NT; nt++) {
            int row = wc * NT * 16 + nt * 16 + m16;
            bfr[nt] = *(const short8*)(sB + row * 32 + quad * 8);
        }
        #pragma unroll
        for (int mt = 0; mt < 4; mt++)
            #pragma unroll
            for (int nt = 0; nt < NT; nt++)
                acc[mt][nt] = __builtin_amdgcn_mfma_f32_16x16x32_bf16(
                    af[mt], bfr[nt], acc[mt][nt], 0, 0, 0);
        __syncthreads();
    }
}

#define EPI_IDX() \
    const int tid = threadIdx.x; \
    const int wave = tid >> 6, lane = tid & 63; \
    const int wr = wave >> 1, wc = wave & 1; \
    const int quad = lane >> 4, m16 = lane & 15;

// ---------------- weight transpose + convert: src (R,C) f32 -> dst (C,R) bf16
__global__ __launch_bounds__(256) void k_transpose(
    const float* __restrict__ src, bf16* __restrict__ dst, int R, int C)
{
    __shared__ float tile[32][33];
    const int l = blockIdx.z;
    src += (size_t)l * R * C;
    dst += (size_t)l * R * C;
    int c0 = blockIdx.x * 32, r0 = blockIdx.y * 32;
    int tx = threadIdx.x & 31, ty = threadIdx.x >> 5; // 32 x 8
    #pragma unroll
    for (int i = 0; i < 32; i += 8)
        tile[ty + i][tx] = src[(size_t)(r0 + ty + i) * C + c0 + tx];
    __syncthreads();
    #pragma unroll
    for (int i = 0; i < 32; i += 8)
        dst[(size_t)(c0 + ty + i) * R + r0 + tx] = __float2bfloat16(tile[tx][ty + i]);
}

// ---------------- layernorm: x (2048,768) f32 -> out bf16 --------------
__global__ __launch_bounds__(256) void k_ln(
    const float* __restrict__ x, const float* __restrict__ g,
    const float* __restrict__ b, bf16* __restrict__ out)
{
    const int row = blockIdx.x;
    const float* xr = x + (size_t)row * H;
    const int tid = threadIdx.x;
    float v0 = xr[tid], v1 = xr[tid + 256], v2 = xr[tid + 512];
    float mean = block_sum256(v0 + v1 + v2) * (1.0f / H);
    float d0 = v0 - mean, d1 = v1 - mean, d2 = v2 - mean;
    float var = block_sum256(d0 * d0 + d1 * d1 + d2 * d2) * (1.0f / H);
    float rs = rsqrtf(var + 1e-5f);
    bf16* orow = out + (size_t)row * H;
    orow[tid]       = __float2bfloat16(d0 * rs * g[tid]       + b[tid]);
    orow[tid + 256] = __float2bfloat16(d1 * rs * g[tid + 256] + b[tid + 256]);
    orow[tid + 512] = __float2bfloat16(d2 * rs * g[tid + 512] + b[tid + 512]);
}

// ---------------- fused QKV GEMM ---------------------------------------
// grid (16, 18): y -> mat = y/6 (0=q,1=k,2=v), col block = y%6
__global__ __launch_bounds__(256, 2) void k_qkv(
    const bf16* __restrict__ h,
    const bf16* __restrict__ Wqt, const bf16* __restrict__ Wkt, const bf16* __restrict__ Wvt,
    const float* __restrict__ bq, const float* __restrict__ bk, const float* __restrict__ bv,
    bf16* __restrict__ qb, bf16* __restrict__ kb, bf16* __restrict__ vtb)
{
    const int bm = blockIdx.x, bc = blockIdx.y;
    const int mat = bc / 6, nc = (bc % 6) * 128;
    const bf16* Bt = (mat == 0 ? Wqt : (mat == 1 ? Wkt : Wvt)) + (size_t)nc * H;
    const float* bias = (mat == 0 ? bq : (mat == 1 ? bk : bv));
    f32x4 acc[4][4];
    for (int a = 0; a < 4; a++) for (int bb = 0; bb < 4; bb++)
        for (int i = 0; i < 4; i++) acc[a][bb][i] = 0.0f;
    gemm_core<4>(h + (size_t)bm * 128 * H, H, Bt, H, H, acc);
    EPI_IDX();
    #pragma unroll
    for (int mt = 0; mt < 4; mt++)
        #pragma unroll
        for (int nt = 0; nt < 4; nt++)
            #pragma unroll
            for (int i = 0; i < 4; i++) {
                int r = bm * 128 + wr * 64 + mt * 16 + quad * 4 + i;
                int c = nc + wc * 64 + nt * 16 + m16;
                float v = acc[mt][nt][i] + bias[c];
                int t = r >> 2, b = r & 3, hh = c >> 6, d = c & 63;
                int n = b * NH + hh;
                if (mat == 0)
                    qb[((size_t)(n * T + t)) * HD + d] = __float2bfloat16(v * SCALE);
                else if (mat == 1)
                    kb[((size_t)(n * T + t)) * HD + d] = __float2bfloat16(v);
                else
                    vtb[((size_t)(n * HD + d)) * T + t] = __float2bfloat16(v);
            }
}

// ---------------- scores GEMM: per head S = q k^T + bias, *decay, mask --
// grid (4, 4, 48)
__global__ __launch_bounds__(256, 2) void k_scores(
    const bf16* __restrict__ qb, const bf16* __restrict__ kb,
    const float* __restrict__ abias, const float* __restrict__ decay,
    const int* __restrict__ am, float* __restrict__ sb)
{
    const int n = blockIdx.z;
    const int b = n / NH;
    f32x4 acc[4][4];
    for (int a = 0; a < 4; a++) for (int bb = 0; bb < 4; bb++)
        for (int i = 0; i < 4; i++) acc[a][bb][i] = 0.0f;
    gemm_core<4>(qb + ((size_t)n * T + blockIdx.x * 128) * HD, HD,
                 kb + ((size_t)n * T + blockIdx.y * 128) * HD, HD, HD, acc);
    EPI_IDX();
    #pragma unroll
    for (int mt = 0; mt < 4; mt++)
        #pragma unroll
        for (int nt = 0; nt < 4; nt++)
            #pragma unroll
            for (int i = 0; i < 4; i++) {
                int t = blockIdx.x * 128 + wr * 64 + mt * 16 + quad * 4 + i;
                int s = blockIdx.y * 128 + wc * 64 + nt * 16 + m16;
                size_t idx = ((size_t)n * T + t) * T + s;
                float v = (acc[mt][nt][i] + abias[idx]) * decay[idx];
                bool dead = (!(am[b * T + t] && am[b * T + s])) || (t >= 1 && s == 0);
                sb[idx] = dead ? -__builtin_inff() : v;
            }
}

// ---------------- softmax over s: sb (48,512,512) f32 -> pb bf16 --------
__global__ __launch_bounds__(256) void k_softmax(
    const float* __restrict__ sb, bf16* __restrict__ pb)
{
    const int n = blockIdx.y, t = blockIdx.x;
    const float* row = sb + ((size_t)n * T + t) * T;
    const int tid = threadIdx.x;
    float a0 = row[tid], a1 = row[tid + 256];
    float m = block_max256(fmaxf(a0, a1));
    float e0 = expf(a0 - m), e1 = expf(a1 - m);
    float inv = 1.0f / block_sum256(e0 + e1);
    bf16* orow = pb + ((size_t)n * T + t) * T;
    orow[tid]       = __float2bfloat16(e0 * inv);
    orow[tid + 256] = __float2bfloat16(e1 * inv);
}

// ---------------- PV GEMM: attn = P @ V, write token-major bf16 ---------
// grid (4, 1, 48), tile 128x64
__global__ __launch_bounds__(256, 2) void k_pv(
    const bf16* __restrict__ pb, const bf16* __restrict__ vtb,
    bf16* __restrict__ ab)
{
    const int n = blockIdx.z;
    f32x4 acc[4][2];
    for (int a = 0; a < 4; a++) for (int bb = 0; bb < 2; bb++)
        for (int i = 0; i < 4; i++) acc[a][bb][i] = 0.0f;
    gemm_core<2>(pb + ((size_t)n * T + blockIdx.x * 128) * T, T,
                 vtb + (size_t)n * HD * T, T, T, acc);
    EPI_IDX();
    const int b = n / NH, hh = n % NH;
    #pragma unroll
    for (int mt = 0; mt < 4; mt++)
        #pragma unroll
        for (int nt = 0; nt < 2; nt++)
            #pragma unroll
            for (int i = 0; i < 4; i++) {
                int t = blockIdx.x * 128 + wr * 64 + mt * 16 + quad * 4 + i;
                int d = wc * 32 + nt * 16 + m16;
                ab[((size_t)(t * BB + b)) * H + hh * HD + d] = __float2bfloat16(acc[mt][nt][i]);
            }
}

// ---------------- attn out proj + residual, split-K=2, atomic epilogue --
// grid (16, 6, 2)
__global__ __launch_bounds__(256, 2) void k_out(
    const bf16* __restrict__ ab, const bf16* __restrict__ Wot,
    const float* __restrict__ bo, float* __restrict__ x)
{
    const int bm = blockIdx.x, bn = blockIdx.y, kc = blockIdx.z;
    f32x4 acc[4][4];
    for (int a = 0; a < 4; a++) for (int bb = 0; bb < 4; bb++)
        for (int i = 0; i < 4; i++) acc[a][bb][i] = 0.0f;
    gemm_core<4>(ab + (size_t)bm * 128 * H + kc * 384, H,
                 Wot + (size_t)bn * 128 * H + kc * 384, H, 384, acc);
    EPI_IDX();
    #pragma unroll
    for (int mt = 0; mt < 4; mt++)
        #pragma unroll
        for (int nt = 0; nt < 4; nt++)
            #pragma unroll
            for (int i = 0; i < 4; i++) {
                int r = bm * 128 + wr * 64 + mt * 16 + quad * 4 + i;
                int c = bn * 128 + wc * 64 + nt * 16 + m16;
                size_t idx = (size_t)r * H + c;
                float v = acc[mt][nt][i] + (kc == 0 ? bo[c] : 0.0f);
                atomicAdd(&x[idx], v);
            }
}

// ---------------- FFN1 + gelu -------------------------------------------
__global__ __launch_bounds__(256, 2) void k_ffn1(
    const bf16* __restrict__ h, const bf16* __restrict__ W1t,
    const float* __restrict__ b1, bf16* __restrict__ gb)
{
    const int bm = blockIdx.x, bn = blockIdx.y;
    f32x4 acc[4][4];
    for (int a = 0; a < 4; a++) for (int bb = 0; bb < 4; bb++)
        for (int i = 0; i < 4; i++) acc[a][bb][i] = 0.0f;
    gemm_core<4>(h + (size_t)bm * 128 * H, H, W1t + (size_t)bn * 128 * H, H, H, acc);
    EPI_IDX();
    #pragma unroll
    for (int mt = 0; mt < 4; mt++)
        #pragma unroll
        for (int nt = 0; nt < 4; nt++)
            #pragma unroll
            for (int i = 0; i < 4; i++) {
                int r = bm * 128 + wr * 64 + mt * 16 + quad * 4 + i;
                int c = bn * 128 + wc * 64 + nt * 16 + m16;
                float u = acc[mt][nt][i] + b1[c];
                float gl = 0.5f * u * (1.0f + tanhf(0.7978845608028654f * (u + 0.044715f * u * u * u)));
                gb[(size_t)r * FF + c] = __float2bfloat16(gl);
            }
}

// ---------------- FFN2 + residual, split-K=4, atomic epilogue -----------
// grid (16, 6, 4)
__global__ __launch_bounds__(256, 2) void k_ffn2(
    const bf16* __restrict__ gb, const bf16* __restrict__ W2t,
    const float* __restrict__ b2, float* __restrict__ x)
{
    const int bm = blockIdx.x, bn = blockIdx.y, kc = blockIdx.z;
    f32x4 acc[4][4];
    for (int a = 0; a < 4; a++) for (int bb = 0; bb < 4; bb++)
        for (int i = 0; i < 4; i++) acc[a][bb][i] = 0.0f;
    gemm_core<4>(gb + (size_t)bm * 128 * FF + kc * 768, FF,
                 W2t + (size_t)bn * 128 * FF + kc * 768, FF, 768, acc);
    EPI_IDX();
    #pragma unroll
    for (int mt = 0; mt < 4; mt++)
        #pragma unroll
        for (int nt = 0; nt < 4; nt++)
            #pragma unroll
            for (int i = 0; i < 4; i++) {
                int r = bm * 128 + wr * 64 + mt * 16 + quad * 4 + i;
                int c = bn * 128 + wc * 64 + nt * 16 + m16;
                size_t idx = (size_t)r * H + c;
                float v = acc[mt][nt][i] + (kc == 0 ? b2[c] : 0.0f);
                atomicAdd(&x[idx], v);
            }
}

// ---------------- host ---------------------------------------------------
extern "C" void kernel_launch(void* const* d_in, const int* in_sizes, int n_in,
                              void* d_out, int out_size, void* d_ws, size_t ws_size,
                              hipStream_t stream) {
    const float* x_in  = (const float*)d_in[0];
    const float* abias = (const float*)d_in[1];
    const float* decay = (const float*)d_in[2];
    const int*   am    = (const int*)d_in[3];
    const float* Wq = (const float*)d_in[4];
    const float* bq = (const float*)d_in[5];
    const float* Wk = (const float*)d_in[6];
    const float* bk = (const float*)d_in[7];
    const float* Wv = (const float*)d_in[8];
    const float* bv = (const float*)d_in[9];
    const float* Wo = (const float*)d_in[10];
    const float* bo = (const float*)d_in[11];
    const float* ln1g = (const float*)d_in[12];
    const float* ln1b = (const float*)d_in[13];
    const float* ln2g = (const float*)d_in[14];
    const float* ln2b = (const float*)d_in[15];
    const float* W1 = (const float*)d_in[16];
    const float* b1 = (const float*)d_in[17];
    const float* W2 = (const float*)d_in[18];
    const float* b2 = (const float*)d_in[19];
    float* x = (float*)d_out;

    char* p = (char*)d_ws;
    auto alloc = [&](size_t bytes) {
        char* r = p;
        p += (bytes + 255) & ~(size_t)255;
        return r;
    };
    bf16* Wqt = (bf16*)alloc((size_t)LYR * H * H * 2);
    bf16* Wkt = (bf16*)alloc((size_t)LYR * H * H * 2);
    bf16* Wvt = (bf16*)alloc((size_t)LYR * H * H * 2);
    bf16* Wot = (bf16*)alloc((size_t)LYR * H * H * 2);
    bf16* W1t = (bf16*)alloc((size_t)LYR * H * FF * 2);
    bf16* W2t = (bf16*)alloc((size_t)LYR * H * FF * 2);
    bf16* hbuf = (bf16*)alloc((size_t)M_TOK * H * 2);
    bf16* qb   = (bf16*)alloc((size_t)BB * NH * T * HD * 2);   // also reused as ab
    bf16* kb   = (bf16*)alloc((size_t)BB * NH * T * HD * 2);
    bf16* vtb  = (bf16*)alloc((size_t)BB * NH * T * HD * 2);
    float* sb  = (float*)alloc((size_t)BB * NH * T * T * 4);
    bf16* pb   = (bf16*)alloc((size_t)BB * NH * T * T * 2);    // also reused as gb
    bf16* ab = qb;
    bf16* gb = pb;

    hipMemcpyAsync(x, x_in, (size_t)M_TOK * H * 4, hipMemcpyDeviceToDevice, stream);

    dim3 blk(256);
    k_transpose<<<dim3(H / 32, H / 32, LYR), blk, 0, stream>>>(Wq, Wqt, H, H);
    k_transpose<<<dim3(H / 32, H / 32, LYR), blk, 0, stream>>>(Wk, Wkt, H, H);
    k_transpose<<<dim3(H / 32, H / 32, LYR), blk, 0, stream>>>(Wv, Wvt, H, H);
    k_transpose<<<dim3(H / 32, H / 32, LYR), blk, 0, stream>>>(Wo, Wot, H, H);
    k_transpose<<<dim3(FF / 32, H / 32, LYR), blk, 0, stream>>>(W1, W1t, H, FF);
    k_transpose<<<dim3(H / 32, FF / 32, LYR), blk, 0, stream>>>(W2, W2t, FF, H);

    for (int l = 0; l < LYR; l++) {
        size_t wo = (size_t)l * H * H;
        size_t wf = (size_t)l * H * FF;
        k_ln<<<dim3(M_TOK), blk, 0, stream>>>(x, ln1g + l * H, ln1b + l * H, hbuf);
        k_qkv<<<dim3(16, 18), blk, 0, stream>>>(hbuf, Wqt + wo, Wkt + wo, Wvt + wo,
                                                bq + l * H, bk + l * H, bv + l * H,
                                                qb, kb, vtb);
        k_scores<<<dim3(4, 4, 48), blk, 0, stream>>>(qb, kb, abias, decay, am, sb);
        k_softmax<<<dim3(T, 48), blk, 0, stream>>>(sb, pb);
        k_pv<<<dim3(4, 1, 48), blk, 0, stream>>>(pb, vtb, ab);
        k_out<<<dim3(16, 6, 2), blk, 0, stream>>>(ab, Wot + wo, bo + l * H, x);
        k_ln<<<dim3(M_TOK), blk, 0, stream>>>(x, ln2g + l * H, ln2b + l * H, hbuf);
        k_ffn1<<<dim3(16, 24), blk, 0, stream>>>(hbuf, W1t + wf, b1 + l * FF, gb);
        k_ffn2<<<dim3(16, 6, 4), blk, 0, stream>>>(gb, W2t + wf, b2 + l * H, x);
    }
}

// Round 3
// 1276.636 us; speedup vs baseline: 2.3036x; 1.2370x over previous
//
#include <hip/hip_runtime.h>
#include <hip/hip_bf16.h>

#define LYR 6
#define H 768
#define NH 12
#define HD 64
#define FF 3072
#define T 512
#define BB 4
#define M_TOK 2048
#define SCALE 0.125f

typedef __hip_bfloat16 bf16;
typedef __attribute__((ext_vector_type(8))) short short8;
typedef __attribute__((ext_vector_type(4))) float f32x4;

// ---------------- block reduction helpers (256 threads) ----------------
__device__ __forceinline__ float block_sum256(float v) {
    __shared__ float sm[4];
    #pragma unroll
    for (int o = 32; o > 0; o >>= 1) v += __shfl_down(v, o);
    if ((threadIdx.x & 63) == 0) sm[threadIdx.x >> 6] = v;
    __syncthreads();
    float r = sm[0] + sm[1] + sm[2] + sm[3];
    __syncthreads();
    return r;
}

// async global->LDS, 16 B per lane; lds base must be wave-uniform
__device__ __forceinline__ void gload_lds16(const bf16* g, bf16* l) {
    __builtin_amdgcn_global_load_lds(
        (const __attribute__((address_space(1))) void*)g,
        (__attribute__((address_space(3))) void*)l, 16, 0, 0);
}

// ---------------- GEMM core: C[128 x NT*32] = A(128,K) * Bt(NT*32,K)^T ----
template<int NT>
__device__ __forceinline__ void gemm_core(
    const bf16* __restrict__ A, int lda,
    const bf16* __restrict__ Bt, int ldb,
    int K, f32x4 acc[4][NT])
{
    constexpr int BN = NT * 32;
    __shared__ bf16 sA[128 * 32];
    __shared__ bf16 sB[BN * 32];
    const int tid = threadIdx.x;
    const int wave = tid >> 6, lane = tid & 63;
    const int wr = wave >> 1, wc = wave & 1;
    const int quad = lane >> 4, m16 = lane & 15;

    for (int k0 = 0; k0 < K; k0 += 32) {
        #pragma unroll
        for (int i = 0; i < 2; i++) {
            int c = tid + i * 256; int r = c >> 2, k8 = c & 3;
            gload_lds16(A + (size_t)r * lda + k0 + k8 * 8,
                        sA + (i * 256 + wave * 64) * 8);
        }
        #pragma unroll
        for (int i = 0; i < BN / 64; i++) {
            int c = tid + i * 256; int r = c >> 2, k8 = c & 3;
            gload_lds16(Bt + (size_t)r * ldb + k0 + k8 * 8,
                        sB + (i * 256 + wave * 64) * 8);
        }
        __syncthreads();
        short8 af[4], bfr[NT];
        #pragma unroll
        for (int mt = 0; mt < 4; mt++) {
            int row = wr * 64 + mt * 16 + m16;
            af[mt] = *(const short8*)(sA + row * 32 + quad * 8);
        }
        #pragma unroll
        for (int nt = 0; nt < NT; nt++) {
            int row = wc * NT * 16 + nt * 16 + m16;
            bfr[nt] = *(const short8*)(sB + row * 32 + quad * 8);
        }
        #pragma unroll
        for (int mt = 0; mt < 4; mt++)
            #pragma unroll
            for (int nt = 0; nt < NT; nt++)
                acc[mt][nt] = __builtin_amdgcn_mfma_f32_16x16x32_bf16(
                    af[mt], bfr[nt], acc[mt][nt], 0, 0, 0);
        __syncthreads();
    }
}

#define EPI_IDX() \
    const int tid = threadIdx.x; \
    const int wave = tid >> 6, lane = tid & 63; \
    const int wr = wave >> 1, wc = wave & 1; \
    const int quad = lane >> 4, m16 = lane & 15;

// ---------------- weight transpose + convert: src (R,C) f32 -> dst (C,R) bf16
__global__ __launch_bounds__(256) void k_transpose(
    const float* __restrict__ src, bf16* __restrict__ dst, int R, int C)
{
    __shared__ float tile[32][33];
    const int l = blockIdx.z;
    src += (size_t)l * R * C;
    dst += (size_t)l * R * C;
    int c0 = blockIdx.x * 32, r0 = blockIdx.y * 32;
    int tx = threadIdx.x & 31, ty = threadIdx.x >> 5; // 32 x 8
    #pragma unroll
    for (int i = 0; i < 32; i += 8)
        tile[ty + i][tx] = src[(size_t)(r0 + ty + i) * C + c0 + tx];
    __syncthreads();
    #pragma unroll
    for (int i = 0; i < 32; i += 8)
        dst[(size_t)(c0 + ty + i) * R + r0 + tx] = __float2bfloat16(tile[tx][ty + i]);
}

// ---------------- precompute masked bf16 bias/decay once ----------------
// B1 = dead ? -inf : abias*decay ; D1 = decay.  grid (T, B*NH)
__global__ __launch_bounds__(256) void k_prep(
    const float* __restrict__ abias, const float* __restrict__ decay,
    const int* __restrict__ am, bf16* __restrict__ B1, bf16* __restrict__ D1)
{
    const int n = blockIdx.y, t = blockIdx.x;
    const int b = n / NH;
    const bool amt = am[b * T + t] != 0;
    const size_t base = ((size_t)n * T + t) * T;
    for (int s = threadIdx.x; s < T; s += 256) {
        bool dead = (!(amt && (am[b * T + s] != 0))) || (t >= 1 && s == 0);
        float de = decay[base + s];
        float bd = abias[base + s] * de;
        B1[base + s] = __float2bfloat16(dead ? -__builtin_inff() : bd);
        D1[base + s] = __float2bfloat16(de);
    }
}

// ---------------- layernorm: x (2048,768) f32 -> out bf16 --------------
__global__ __launch_bounds__(256) void k_ln(
    const float* __restrict__ x, const float* __restrict__ g,
    const float* __restrict__ b, bf16* __restrict__ out)
{
    const int row = blockIdx.x;
    const float* xr = x + (size_t)row * H;
    const int tid = threadIdx.x;
    float v0 = xr[tid], v1 = xr[tid + 256], v2 = xr[tid + 512];
    float mean = block_sum256(v0 + v1 + v2) * (1.0f / H);
    float d0 = v0 - mean, d1 = v1 - mean, d2 = v2 - mean;
    float var = block_sum256(d0 * d0 + d1 * d1 + d2 * d2) * (1.0f / H);
    float rs = rsqrtf(var + 1e-5f);
    bf16* orow = out + (size_t)row * H;
    orow[tid]       = __float2bfloat16(d0 * rs * g[tid]       + b[tid]);
    orow[tid + 256] = __float2bfloat16(d1 * rs * g[tid + 256] + b[tid + 256]);
    orow[tid + 512] = __float2bfloat16(d2 * rs * g[tid + 512] + b[tid + 512]);
}

// ---------------- fused QKV GEMM ---------------------------------------
__global__ __launch_bounds__(256, 2) void k_qkv(
    const bf16* __restrict__ h,
    const bf16* __restrict__ Wqt, const bf16* __restrict__ Wkt, const bf16* __restrict__ Wvt,
    const float* __restrict__ bq, const float* __restrict__ bk, const float* __restrict__ bv,
    bf16* __restrict__ qb, bf16* __restrict__ kb, bf16* __restrict__ vtb)
{
    const int bm = blockIdx.x, bc = blockIdx.y;
    const int mat = bc / 6, nc = (bc % 6) * 128;
    const bf16* Bt = (mat == 0 ? Wqt : (mat == 1 ? Wkt : Wvt)) + (size_t)nc * H;
    const float* bias = (mat == 0 ? bq : (mat == 1 ? bk : bv));
    f32x4 acc[4][4];
    for (int a = 0; a < 4; a++) for (int bb = 0; bb < 4; bb++)
        for (int i = 0; i < 4; i++) acc[a][bb][i] = 0.0f;
    gemm_core<4>(h + (size_t)bm * 128 * H, H, Bt, H, H, acc);
    EPI_IDX();
    #pragma unroll
    for (int mt = 0; mt < 4; mt++)
        #pragma unroll
        for (int nt = 0; nt < 4; nt++)
            #pragma unroll
            for (int i = 0; i < 4; i++) {
                int r = bm * 128 + wr * 64 + mt * 16 + quad * 4 + i;
                int c = nc + wc * 64 + nt * 16 + m16;
                float v = acc[mt][nt][i] + bias[c];
                int t = r >> 2, b = r & 3, hh = c >> 6, d = c & 63;
                int n = b * NH + hh;
                if (mat == 0)
                    qb[((size_t)(n * T + t)) * HD + d] = __float2bfloat16(v * SCALE);
                else if (mat == 1)
                    kb[((size_t)(n * T + t)) * HD + d] = __float2bfloat16(v);
                else
                    vtb[((size_t)(n * HD + d)) * T + t] = __float2bfloat16(v);
            }
}

// ---------------- fused flash attention: scores+softmax+PV --------------
// grid (T/64, B*NH).  Per block: 64 q rows x full 512 s, one head.
// Wave w owns q rows [w*16, w*16+16).  Online softmax, O accum in regs.
__global__ __launch_bounds__(256, 2) void k_attn(
    const bf16* __restrict__ qb, const bf16* __restrict__ kb,
    const bf16* __restrict__ vtb, const bf16* __restrict__ B1,
    const bf16* __restrict__ D1, bf16* __restrict__ ab)
{
    __shared__ bf16 Qs[64][72];       // padded: 2-way bank max
    __shared__ bf16 Ks[128][72];
    __shared__ bf16 Vs[64][136];
    __shared__ bf16 Ps[4][16][136];
    const int n = blockIdx.y, q0 = blockIdx.x * 64;
    const int tid = threadIdx.x, wave = tid >> 6, lane = tid & 63;
    const int quad = lane >> 4, m16 = lane & 15;

    // stage Q (64 rows x 64 cols)
    #pragma unroll
    for (int it = 0; it < 2; it++) {
        int c = it * 256 + tid, r = c >> 3, c8 = c & 7;
        *(uint4*)&Qs[r][c8 * 8] =
            *(const uint4*)(qb + ((size_t)n * T + q0 + r) * HD + c8 * 8);
    }

    f32x4 oacc[4];
    float m_i[4], l_i[4];
    #pragma unroll
    for (int i = 0; i < 4; i++) { m_i[i] = -__builtin_inff(); l_i[i] = 0.0f; }
    #pragma unroll
    for (int dt = 0; dt < 4; dt++)
        #pragma unroll
        for (int i = 0; i < 4; i++) oacc[dt][i] = 0.0f;
    __syncthreads();

    for (int st = 0; st < 4; st++) {
        // stage K tile (128 x 64) and V^T tile (64 x 128)
        #pragma unroll
        for (int it = 0; it < 4; it++) {
            int c = it * 256 + tid, r = c >> 3, c8 = c & 7;
            *(uint4*)&Ks[r][c8 * 8] =
                *(const uint4*)(kb + ((size_t)n * T + st * 128 + r) * HD + c8 * 8);
        }
        #pragma unroll
        for (int it = 0; it < 4; it++) {
            int c = it * 256 + tid, d = c >> 4, s8 = c & 15;
            *(uint4*)&Vs[d][s8 * 8] =
                *(const uint4*)(vtb + ((size_t)n * HD + d) * T + st * 128 + s8 * 8);
        }
        __syncthreads();

        // S = Q K^T : wave's 16 rows x 128 cols
        f32x4 sacc[8];
        #pragma unroll
        for (int ct = 0; ct < 8; ct++)
            #pragma unroll
            for (int i = 0; i < 4; i++) sacc[ct][i] = 0.0f;
        #pragma unroll
        for (int ks = 0; ks < 2; ks++) {
            short8 af = *(const short8*)&Qs[wave * 16 + m16][ks * 32 + quad * 8];
            #pragma unroll
            for (int ct = 0; ct < 8; ct++) {
                short8 bfr = *(const short8*)&Ks[ct * 16 + m16][ks * 32 + quad * 8];
                sacc[ct] = __builtin_amdgcn_mfma_f32_16x16x32_bf16(af, bfr, sacc[ct], 0, 0, 0);
            }
        }

        // epilogue: val = qk * D1 + B1   (C layout: col=m16, row=quad*4+i)
        const int trow = q0 + wave * 16 + quad * 4;
        float val[8][4];
        #pragma unroll
        for (int ct = 0; ct < 8; ct++) {
            int s = st * 128 + ct * 16 + m16;
            #pragma unroll
            for (int i = 0; i < 4; i++) {
                size_t idx = ((size_t)n * T + trow + i) * T + s;
                val[ct][i] = sacc[ct][i] * __bfloat162float(D1[idx])
                           + __bfloat162float(B1[idx]);
            }
        }

        // online softmax per row
        float alpha[4], mn[4];
        #pragma unroll
        for (int i = 0; i < 4; i++) {
            float rm = val[0][i];
            #pragma unroll
            for (int ct = 1; ct < 8; ct++) rm = fmaxf(rm, val[ct][i]);
            #pragma unroll
            for (int o = 8; o > 0; o >>= 1) rm = fmaxf(rm, __shfl_xor(rm, o));
            mn[i] = fmaxf(m_i[i], rm);
            alpha[i] = __expf(m_i[i] - mn[i]);
            m_i[i] = mn[i];
        }
        float rs[4] = {0.0f, 0.0f, 0.0f, 0.0f};
        #pragma unroll
        for (int ct = 0; ct < 8; ct++) {
            #pragma unroll
            for (int i = 0; i < 4; i++) {
                float pv = __expf(val[ct][i] - mn[i]);
                rs[i] += pv;
                Ps[wave][quad * 4 + i][ct * 16 + m16] = __float2bfloat16(pv);
            }
        }
        #pragma unroll
        for (int i = 0; i < 4; i++) {
            #pragma unroll
            for (int o = 8; o > 0; o >>= 1) rs[i] += __shfl_xor(rs[i], o);
            l_i[i] = l_i[i] * alpha[i] + rs[i];
        }
        #pragma unroll
        for (int dt = 0; dt < 4; dt++)
            #pragma unroll
            for (int i = 0; i < 4; i++) oacc[dt][i] *= alpha[i];

        // O += P V   (A from Ps, B from Vs)
        #pragma unroll
        for (int ks = 0; ks < 4; ks++) {
            short8 af = *(const short8*)&Ps[wave][m16][ks * 32 + quad * 8];
            #pragma unroll
            for (int dt = 0; dt < 4; dt++) {
                short8 bfr = *(const short8*)&Vs[dt * 16 + m16][ks * 32 + quad * 8];
                oacc[dt] = __builtin_amdgcn_mfma_f32_16x16x32_bf16(af, bfr, oacc[dt], 0, 0, 0);
            }
        }
        __syncthreads();
    }

    // write O / l  -> ab token-major (t*BB+b, hh*64+d)
    const int b = n / NH, hh = n % NH;
    #pragma unroll
    for (int i = 0; i < 4; i++) {
        int t = q0 + wave * 16 + quad * 4 + i;
        float inv = 1.0f / l_i[i];
        #pragma unroll
        for (int dt = 0; dt < 4; dt++) {
            int d = dt * 16 + m16;
            ab[((size_t)(t * BB + b)) * H + hh * HD + d] =
                __float2bfloat16(oacc[dt][i] * inv);
        }
    }
}

// ---------------- attn out proj + residual, split-K=2, atomic epilogue --
__global__ __launch_bounds__(256, 2) void k_out(
    const bf16* __restrict__ ab, const bf16* __restrict__ Wot,
    const float* __restrict__ bo, float* __restrict__ x)
{
    const int bm = blockIdx.x, bn = blockIdx.y, kc = blockIdx.z;
    f32x4 acc[4][4];
    for (int a = 0; a < 4; a++) for (int bb = 0; bb < 4; bb++)
        for (int i = 0; i < 4; i++) acc[a][bb][i] = 0.0f;
    gemm_core<4>(ab + (size_t)bm * 128 * H + kc * 384, H,
                 Wot + (size_t)bn * 128 * H + kc * 384, H, 384, acc);
    EPI_IDX();
    #pragma unroll
    for (int mt = 0; mt < 4; mt++)
        #pragma unroll
        for (int nt = 0; nt < 4; nt++)
            #pragma unroll
            for (int i = 0; i < 4; i++) {
                int r = bm * 128 + wr * 64 + mt * 16 + quad * 4 + i;
                int c = bn * 128 + wc * 64 + nt * 16 + m16;
                size_t idx = (size_t)r * H + c;
                float v = acc[mt][nt][i] + (kc == 0 ? bo[c] : 0.0f);
                atomicAdd(&x[idx], v);
            }
}

// ---------------- FFN1 + gelu -------------------------------------------
__global__ __launch_bounds__(256, 2) void k_ffn1(
    const bf16* __restrict__ h, const bf16* __restrict__ W1t,
    const float* __restrict__ b1, bf16* __restrict__ gb)
{
    const int bm = blockIdx.x, bn = blockIdx.y;
    f32x4 acc[4][4];
    for (int a = 0; a < 4; a++) for (int bb = 0; bb < 4; bb++)
        for (int i = 0; i < 4; i++) acc[a][bb][i] = 0.0f;
    gemm_core<4>(h + (size_t)bm * 128 * H, H, W1t + (size_t)bn * 128 * H, H, H, acc);
    EPI_IDX();
    #pragma unroll
    for (int mt = 0; mt < 4; mt++)
        #pragma unroll
        for (int nt = 0; nt < 4; nt++)
            #pragma unroll
            for (int i = 0; i < 4; i++) {
                int r = bm * 128 + wr * 64 + mt * 16 + quad * 4 + i;
                int c = bn * 128 + wc * 64 + nt * 16 + m16;
                float u = acc[mt][nt][i] + b1[c];
                float gl = 0.5f * u * (1.0f + tanhf(0.7978845608028654f * (u + 0.044715f * u * u * u)));
                gb[(size_t)r * FF + c] = __float2bfloat16(gl);
            }
}

// ---------------- FFN2 + residual, split-K=4, atomic epilogue -----------
__global__ __launch_bounds__(256, 2) void k_ffn2(
    const bf16* __restrict__ gb, const bf16* __restrict__ W2t,
    const float* __restrict__ b2, float* __restrict__ x)
{
    const int bm = blockIdx.x, bn = blockIdx.y, kc = blockIdx.z;
    f32x4 acc[4][4];
    for (int a = 0; a < 4; a++) for (int bb = 0; bb < 4; bb++)
        for (int i = 0; i < 4; i++) acc[a][bb][i] = 0.0f;
    gemm_core<4>(gb + (size_t)bm * 128 * FF + kc * 768, FF,
                 W2t + (size_t)bn * 128 * FF + kc * 768, FF, 768, acc);
    EPI_IDX();
    #pragma unroll
    for (int mt = 0; mt < 4; mt++)
        #pragma unroll
        for (int nt = 0; nt < 4; nt++)
            #pragma unroll
            for (int i = 0; i < 4; i++) {
                int r = bm * 128 + wr * 64 + mt * 16 + quad * 4 + i;
                int c = bn * 128 + wc * 64 + nt * 16 + m16;
                size_t idx = (size_t)r * H + c;
                float v = acc[mt][nt][i] + (kc == 0 ? b2[c] : 0.0f);
                atomicAdd(&x[idx], v);
            }
}

// ---------------- host ---------------------------------------------------
extern "C" void kernel_launch(void* const* d_in, const int* in_sizes, int n_in,
                              void* d_out, int out_size, void* d_ws, size_t ws_size,
                              hipStream_t stream) {
    const float* x_in  = (const float*)d_in[0];
    const float* abias = (const float*)d_in[1];
    const float* decay = (const float*)d_in[2];
    const int*   am    = (const int*)d_in[3];
    const float* Wq = (const float*)d_in[4];
    const float* bq = (const float*)d_in[5];
    const float* Wk = (const float*)d_in[6];
    const float* bk = (const float*)d_in[7];
    const float* Wv = (const float*)d_in[8];
    const float* bv = (const float*)d_in[9];
    const float* Wo = (const float*)d_in[10];
    const float* bo = (const float*)d_in[11];
    const float* ln1g = (const float*)d_in[12];
    const float* ln1b = (const float*)d_in[13];
    const float* ln2g = (const float*)d_in[14];
    const float* ln2b = (const float*)d_in[15];
    const float* W1 = (const float*)d_in[16];
    const float* b1 = (const float*)d_in[17];
    const float* W2 = (const float*)d_in[18];
    const float* b2 = (const float*)d_in[19];
    float* x = (float*)d_out;

    char* p = (char*)d_ws;
    auto alloc = [&](size_t bytes) {
        char* r = p;
        p += (bytes + 255) & ~(size_t)255;
        return r;
    };
    bf16* Wqt = (bf16*)alloc((size_t)LYR * H * H * 2);
    bf16* Wkt = (bf16*)alloc((size_t)LYR * H * H * 2);
    bf16* Wvt = (bf16*)alloc((size_t)LYR * H * H * 2);
    bf16* Wot = (bf16*)alloc((size_t)LYR * H * H * 2);
    bf16* W1t = (bf16*)alloc((size_t)LYR * H * FF * 2);
    bf16* W2t = (bf16*)alloc((size_t)LYR * H * FF * 2);
    bf16* hbuf = (bf16*)alloc((size_t)M_TOK * H * 2);
    bf16* qb   = (bf16*)alloc((size_t)BB * NH * T * HD * 2);
    bf16* kb   = (bf16*)alloc((size_t)BB * NH * T * HD * 2);
    bf16* vtb  = (bf16*)alloc((size_t)BB * NH * T * HD * 2);
    bf16* ab   = (bf16*)alloc((size_t)BB * NH * T * HD * 2);
    bf16* B1   = (bf16*)alloc((size_t)BB * NH * T * T * 2);
    bf16* D1   = (bf16*)alloc((size_t)BB * NH * T * T * 2);
    bf16* gb   = (bf16*)alloc((size_t)M_TOK * FF * 2);

    hipMemcpyAsync(x, x_in, (size_t)M_TOK * H * 4, hipMemcpyDeviceToDevice, stream);

    dim3 blk(256);
    k_prep<<<dim3(T, BB * NH), blk, 0, stream>>>(abias, decay, am, B1, D1);
    k_transpose<<<dim3(H / 32, H / 32, LYR), blk, 0, stream>>>(Wq, Wqt, H, H);
    k_transpose<<<dim3(H / 32, H / 32, LYR), blk, 0, stream>>>(Wk, Wkt, H, H);
    k_transpose<<<dim3(H / 32, H / 32, LYR), blk, 0, stream>>>(Wv, Wvt, H, H);
    k_transpose<<<dim3(H / 32, H / 32, LYR), blk, 0, stream>>>(Wo, Wot, H, H);
    k_transpose<<<dim3(FF / 32, H / 32, LYR), blk, 0, stream>>>(W1, W1t, H, FF);
    k_transpose<<<dim3(H / 32, FF / 32, LYR), blk, 0, stream>>>(W2, W2t, FF, H);

    for (int l = 0; l < LYR; l++) {
        size_t wo = (size_t)l * H * H;
        size_t wf = (size_t)l * H * FF;
        k_ln<<<dim3(M_TOK), blk, 0, stream>>>(x, ln1g + l * H, ln1b + l * H, hbuf);
        k_qkv<<<dim3(16, 18), blk, 0, stream>>>(hbuf, Wqt + wo, Wkt + wo, Wvt + wo,
                                                bq + l * H, bk + l * H, bv + l * H,
                                                qb, kb, vtb);
        k_attn<<<dim3(T / 64, BB * NH), blk, 0, stream>>>(qb, kb, vtb, B1, D1, ab);
        k_out<<<dim3(16, 6, 2), blk, 0, stream>>>(ab, Wot + wo, bo + l * H, x);
        k_ln<<<dim3(M_TOK), blk, 0, stream>>>(x, ln2g + l * H, ln2b + l * H, hbuf);
        k_ffn1<<<dim3(16, 24), blk, 0, stream>>>(hbuf, W1t + wf, b1 + l * FF, gb);
        k_ffn2<<<dim3(16, 6, 4), blk, 0, stream>>>(gb, W2t + wf, b2 + l * H, x);
    }
}